// Round 10
// baseline (43.830 us; speedup 1.0000x reference)
//
#include <hip/hip_runtime.h>

#define B_ 1024
#define N_ 20000
#define M_ 10000
#define K_ 8
#define OBS_W_ 200
#define TPB 1024
#define NV4 (N_ / 4)      // 5000 float4 per row
#define NLOAD 5           // ceil(NV4 / TPB)
#define NCHK 10           // ceil(M_ / TPB)

constexpr float EPS_   = 1e-6f;
constexpr float LN2_   = 0.69314718055994530942f;
constexpr float LOG2E_ = 1.4426950408889634f;

typedef _Float16 f16x2 __attribute__((ext_vector_type(2)));
typedef _Float16 f16x8 __attribute__((ext_vector_type(8)));

// tanh(x/2) = 1 - 2/(exp(x)+1), via hardware v_exp_f32 / v_rcp_f32.
__device__ __forceinline__ float tanh_half_fast(float x) {
    float e = __builtin_amdgcn_exp2f(x * LOG2E_);
    return 1.0f - 2.0f * __builtin_amdgcn_rcpf(e + 1.0f);
}

__device__ __forceinline__ float clampp(float p) {
    return fminf(fmaxf(p, -1.0f + EPS_), 1.0f - EPS_);
}

// w-product for one check m against a 2-row buffer: w0*w1, w = 1+(1-2y)p.
__device__ __forceinline__ float wprod2(const f16x2* __restrict__ t2,
                                        const float* __restrict__ synA,
                                        const float* __restrict__ synB,
                                        const int4* __restrict__ cc, int m) {
    int4 c0 = cc[2 * m];
    int4 c1 = cc[2 * m + 1];
    f16x2 g0 = t2[c0.x], g1 = t2[c0.y], g2 = t2[c0.z], g3 = t2[c0.w];
    f16x2 g4 = t2[c1.x], g5 = t2[c1.y], g6 = t2[c1.z], g7 = t2[c1.w];
    f16x2 p  = ((g0 * g1) * (g2 * g3)) * ((g4 * g5) * (g6 * g7));
    float pa = clampp((float)p[0]);
    float pb = clampp((float)p[1]);
    float w0 = fmaf(fmaf(synA[m], -2.0f, 1.0f), pa, 1.0f);
    float w1 = fmaf(fmaf(synB[m], -2.0f, 1.0f), pb, 1.0f);
    return w0 * w1;
}

__device__ __forceinline__ f16x8 pack2(float4 a, float4 c) {
    f16x8 v;
    v[0] = (_Float16)tanh_half_fast(a.x); v[1] = (_Float16)tanh_half_fast(c.x);
    v[2] = (_Float16)tanh_half_fast(a.y); v[3] = (_Float16)tanh_half_fast(c.y);
    v[4] = (_Float16)tanh_half_fast(a.z); v[5] = (_Float16)tanh_half_fast(c.z);
    v[6] = (_Float16)tanh_half_fast(a.w); v[7] = (_Float16)tanh_half_fast(c.w);
    return v;
}

// 4 rows per block, two 2-row f16x2 buffers (2x80KB), deep-prefetch pipeline:
// S_A -> sync -> [issue ALL S_B loads] -> check-A (hides S_B latency)
//     -> pack/write B -> sync -> check-B -> obs -> reduce
template <bool ATOMIC>
__global__ __launch_bounds__(TPB) void decode_loss_dp(
    const float* __restrict__ llrs,
    const float* __restrict__ syndromes,
    const float* __restrict__ observables,
    const int*   __restrict__ chk_cols,
    const int*   __restrict__ obs_cols,
    float* __restrict__ part)
{
    extern __shared__ char smem_raw[];
    f16x2* t2a = reinterpret_cast<f16x2*>(smem_raw);   // rows b0, b0+1
    f16x2* t2b = t2a + N_;                             // rows b0+2, b0+3
    __shared__ float red[TPB / 64];

    const int b0  = 4 * blockIdx.x;
    const int tid = threadIdx.x;

    const float4* r0 = reinterpret_cast<const float4*>(llrs + (size_t)(b0 + 0) * N_);
    const float4* r1 = reinterpret_cast<const float4*>(llrs + (size_t)(b0 + 1) * N_);
    const float4* r2 = reinterpret_cast<const float4*>(llrs + (size_t)(b0 + 2) * N_);
    const float4* r3 = reinterpret_cast<const float4*>(llrs + (size_t)(b0 + 3) * N_);

    // ---- S_A: stage rows b0, b0+1 into buf A ----
    for (int i = tid; i < NV4; i += TPB) {
        *reinterpret_cast<f16x8*>(&t2a[4 * i]) = pack2(r0[i], r1[i]);
    }
    __syncthreads();

    // ---- issue ALL stage-B loads up front (deep prefetch, ~40 VGPR) ----
    float4 pa[NLOAD], pc[NLOAD];
    #pragma unroll
    for (int s = 0; s < NLOAD; ++s) {
        const int i = tid + s * TPB;
        if (i < NV4) { pa[s] = r2[i]; pc[s] = r3[i]; }
    }

    const float* syn0 = syndromes + (size_t)(b0 + 0) * M_;
    const float* syn1 = syndromes + (size_t)(b0 + 1) * M_;
    const float* syn2 = syndromes + (size_t)(b0 + 2) * M_;
    const float* syn3 = syndromes + (size_t)(b0 + 3) * M_;
    const int4*  cc   = reinterpret_cast<const int4*>(chk_cols);

    float acc   = 0.0f;   // sum of log2(w) terms
    int   nterm = 0;

    // ---- check-A on buf A (S_B loads in flight underneath) ----
    #pragma unroll
    for (int it = 0; it < NCHK; it += 2) {
        const int m0 = tid + it * TPB;
        const int m1 = m0 + TPB;
        float w = 1.0f;
        int   c = 0;
        if (m0 < M_) { w *= wprod2(t2a, syn0, syn1, cc, m0); c += 2; }
        if (m1 < M_) { w *= wprod2(t2a, syn0, syn1, cc, m1); c += 2; }
        acc += __builtin_amdgcn_logf(w);   // one log2 per 2 checks x 2 rows
        nterm += c;
    }

    // ---- pack + write buf B (vmcnt waits land here, after ~1250 cyc) ----
    #pragma unroll
    for (int s = 0; s < NLOAD; ++s) {
        const int i = tid + s * TPB;
        if (i < NV4) *reinterpret_cast<f16x8*>(&t2b[4 * i]) = pack2(pa[s], pc[s]);
    }
    __syncthreads();

    // ---- check-B on buf B ----
    #pragma unroll
    for (int it = 0; it < NCHK; it += 2) {
        const int m0 = tid + it * TPB;
        const int m1 = m0 + TPB;
        float w = 1.0f;
        int   c = 0;
        if (m0 < M_) { w *= wprod2(t2b, syn2, syn3, cc, m0); c += 2; }
        if (m1 < M_) { w *= wprod2(t2b, syn2, syn3, cc, m1); c += 2; }
        acc += __builtin_amdgcn_logf(w);
        nterm += c;
    }

    float sum = 0.5f * LN2_ * ((float)nterm - acc);   // BETA = 0.5

    // ---- obs part: 4 waves; wave=row; rows 0,1 buf A, rows 2,3 buf B ----
    if (tid < 256) {
        const int row  = tid >> 6;                    // 0..3, wave-uniform
        const int k    = (tid >> 3) & 7;
        const int seg  = tid & 7;
        const f16x2* tb   = (row < 2) ? t2a : t2b;
        const int    comp = row & 1;
        const int*   oc   = obs_cols + k * OBS_W_ + seg * 25;
        float pr = 1.0f;
        #pragma unroll 5
        for (int w = 0; w < 25; ++w) pr *= (float)tb[oc[w]][comp];
        #pragma unroll
        for (int off = 1; off < 8; off <<= 1) pr *= __shfl_xor(pr, off, 64);
        if (seg == 0) {
            float y  = observables[(size_t)(b0 + row) * K_ + k];
            float p  = clampp(pr);
            float w2 = fmaf(fmaf(y, -2.0f, 1.0f), p, 1.0f);
            sum += 0.5f * LN2_ * (1.0f - __builtin_amdgcn_logf(w2));   // 1-BETA
        }
    }

    // ---- block reduction ----
    for (int off = 32; off > 0; off >>= 1) sum += __shfl_down(sum, off, 64);
    const int lane = tid & 63, wv = tid >> 6;
    if (lane == 0) red[wv] = sum;
    __syncthreads();
    if (tid == 0) {
        float tot = 0.0f;
        #pragma unroll
        for (int i = 0; i < TPB / 64; ++i) tot += red[i];
        if (ATOMIC) atomicAdd(part, tot * (1.0f / (float)B_));
        else        part[blockIdx.x] = tot;
    }
}

__global__ __launch_bounds__(256) void decode_loss_reduce(
    const float* __restrict__ part, float* __restrict__ out, int n)
{
    __shared__ float red[4];
    const int tid = threadIdx.x;
    float s = 0.0f;
    for (int i = tid; i < n; i += 256) s += part[i];
    for (int off = 32; off > 0; off >>= 1) s += __shfl_down(s, off, 64);
    const int lane = tid & 63, wv = tid >> 6;
    if (lane == 0) red[wv] = s;
    __syncthreads();
    if (tid == 0) out[0] = (red[0] + red[1] + red[2] + red[3]) * (1.0f / (float)B_);
}

extern "C" void kernel_launch(void* const* d_in, const int* in_sizes, int n_in,
                              void* d_out, int out_size, void* d_ws, size_t ws_size,
                              hipStream_t stream) {
    const float* llrs        = (const float*)d_in[0];
    const float* syndromes   = (const float*)d_in[1];
    const float* observables = (const float*)d_in[2];
    const int*   chk_cols    = (const int*)d_in[3];
    const int*   obs_cols    = (const int*)d_in[4];
    float*       out         = (float*)d_out;

    const size_t lds_bytes = (size_t)N_ * 2 * sizeof(f16x2);   // 160 000 B
    const int    nblk      = B_ / 4;                           // 256

    (void)hipFuncSetAttribute((const void*)decode_loss_dp<false>,
        hipFuncAttributeMaxDynamicSharedMemorySize, (int)lds_bytes);
    (void)hipFuncSetAttribute((const void*)decode_loss_dp<true>,
        hipFuncAttributeMaxDynamicSharedMemorySize, (int)lds_bytes);

    if (ws_size >= (size_t)nblk * sizeof(float)) {
        float* part = (float*)d_ws;
        decode_loss_dp<false><<<nblk, TPB, lds_bytes, stream>>>(
            llrs, syndromes, observables, chk_cols, obs_cols, part);
        decode_loss_reduce<<<1, 256, 0, stream>>>(part, out, nblk);
    } else {
        hipMemsetAsync(out, 0, sizeof(float), stream);
        decode_loss_dp<true><<<nblk, TPB, lds_bytes, stream>>>(
            llrs, syndromes, observables, chk_cols, obs_cols, out);
    }
}

// Round 11
// 30.934 us; speedup vs baseline: 1.4169x; 1.4169x over previous
//
#include <hip/hip_runtime.h>

#define B_ 1024
#define N_ 20000
#define M_ 10000
#define K_ 8
#define OBS_W_ 200
#define TPB 1024
#define NV4 (N_ / 4)      // 5000 float4 per row

constexpr float EPS_   = 1e-6f;
constexpr float LN2_   = 0.69314718055994530942f;
constexpr float LOG2E_ = 1.4426950408889634f;

typedef _Float16 f16x2 __attribute__((ext_vector_type(2)));
typedef _Float16 f16x8 __attribute__((ext_vector_type(8)));

// tanh(x/2) = 1 - 2/(exp(x)+1), via hardware v_exp_f32 / v_rcp_f32.
__device__ __forceinline__ float tanh_half_fast(float x) {
    float e = __builtin_amdgcn_exp2f(x * LOG2E_);
    return 1.0f - 2.0f * __builtin_amdgcn_rcpf(e + 1.0f);
}

__device__ __forceinline__ float clampp(float p) {
    return fminf(fmaxf(p, -1.0f + EPS_), 1.0f - EPS_);
}

// w-product for one check m against a 2-row buffer: w0*w1, w = 1+(1-2y)p.
__device__ __forceinline__ float wprod2(const f16x2* __restrict__ t2,
                                        const float* __restrict__ synA,
                                        const float* __restrict__ synB,
                                        const int4* __restrict__ cc, int m) {
    int4 c0 = cc[2 * m];
    int4 c1 = cc[2 * m + 1];
    f16x2 g0 = t2[c0.x], g1 = t2[c0.y], g2 = t2[c0.z], g3 = t2[c0.w];
    f16x2 g4 = t2[c1.x], g5 = t2[c1.y], g6 = t2[c1.z], g7 = t2[c1.w];
    f16x2 p  = ((g0 * g1) * (g2 * g3)) * ((g4 * g5) * (g6 * g7));
    float pa = clampp((float)p[0]);
    float pb = clampp((float)p[1]);
    float w0 = fmaf(fmaf(synA[m], -2.0f, 1.0f), pa, 1.0f);
    float w1 = fmaf(fmaf(synB[m], -2.0f, 1.0f), pb, 1.0f);
    return w0 * w1;
}

__device__ __forceinline__ f16x8 pack2(float4 a, float4 c) {
    f16x8 v;
    v[0] = (_Float16)tanh_half_fast(a.x); v[1] = (_Float16)tanh_half_fast(c.x);
    v[2] = (_Float16)tanh_half_fast(a.y); v[3] = (_Float16)tanh_half_fast(c.y);
    v[4] = (_Float16)tanh_half_fast(a.z); v[5] = (_Float16)tanh_half_fast(c.z);
    v[6] = (_Float16)tanh_half_fast(a.w); v[7] = (_Float16)tanh_half_fast(c.w);
    return v;
}

// 4 rows per block, two 2-row f16x2 buffers (2x80KB), WAVE-SPECIALIZED:
//  P1: all waves stage rows 0,1 -> A
//  P2: waves 8-15 run ALL checks of rows 0,1 on A  ||  waves 0-7 stage 2,3 -> B
//  P3: all waves run checks of rows 2,3 on B; obs; reduce
template <bool ATOMIC>
__global__ __launch_bounds__(TPB) void decode_loss_ws(
    const float* __restrict__ llrs,
    const float* __restrict__ syndromes,
    const float* __restrict__ observables,
    const int*   __restrict__ chk_cols,
    const int*   __restrict__ obs_cols,
    float* __restrict__ part)
{
    extern __shared__ char smem_raw[];
    f16x2* t2a = reinterpret_cast<f16x2*>(smem_raw);   // rows b0, b0+1
    f16x2* t2b = t2a + N_;                             // rows b0+2, b0+3
    __shared__ float red[TPB / 64];

    const int b0  = 4 * blockIdx.x;
    const int tid = threadIdx.x;

    const float4* r0 = reinterpret_cast<const float4*>(llrs + (size_t)(b0 + 0) * N_);
    const float4* r1 = reinterpret_cast<const float4*>(llrs + (size_t)(b0 + 1) * N_);
    const float4* r2 = reinterpret_cast<const float4*>(llrs + (size_t)(b0 + 2) * N_);
    const float4* r3 = reinterpret_cast<const float4*>(llrs + (size_t)(b0 + 3) * N_);

    const float* syn0 = syndromes + (size_t)(b0 + 0) * M_;
    const float* syn1 = syndromes + (size_t)(b0 + 1) * M_;
    const float* syn2 = syndromes + (size_t)(b0 + 2) * M_;
    const float* syn3 = syndromes + (size_t)(b0 + 3) * M_;
    const int4*  cc   = reinterpret_cast<const int4*>(chk_cols);

    // ---- P1: all 16 waves stage rows 0,1 into buf A ----
    for (int i = tid; i < NV4; i += TPB) {
        *reinterpret_cast<f16x8*>(&t2a[4 * i]) = pack2(r0[i], r1[i]);
    }
    __syncthreads();

    float acc   = 0.0f;   // sum of log2(w) terms
    int   nterm = 0;

    // ---- P2: wave-specialized overlap ----
    if (tid >= 512) {
        // waves 8-15: ALL M checks for rows 0,1 on buf A (512 threads).
        const int t2id = tid - 512;
        #pragma unroll 2
        for (int it = 0; it < 20; it += 2) {
            const int m0 = t2id + it * 512;
            const int m1 = m0 + 512;
            float w = 1.0f;
            int   c = 0;
            if (m0 < M_) { w *= wprod2(t2a, syn0, syn1, cc, m0); c += 2; }
            if (m1 < M_) { w *= wprod2(t2a, syn0, syn1, cc, m1); c += 2; }
            acc += __builtin_amdgcn_logf(w);   // log2
            nterm += c;
        }
    } else {
        // waves 0-7: stage rows 2,3 into buf B (512 threads).
        for (int i = tid; i < NV4; i += 512) {
            *reinterpret_cast<f16x8*>(&t2b[4 * i]) = pack2(r2[i], r3[i]);
        }
    }
    __syncthreads();

    // ---- P3: all 16 waves: checks for rows 2,3 on buf B ----
    #pragma unroll 2
    for (int it = 0; it < 10; it += 2) {
        const int m0 = tid + it * TPB;
        const int m1 = m0 + TPB;
        float w = 1.0f;
        int   c = 0;
        if (m0 < M_) { w *= wprod2(t2b, syn2, syn3, cc, m0); c += 2; }
        if (m1 < M_) { w *= wprod2(t2b, syn2, syn3, cc, m1); c += 2; }
        acc += __builtin_amdgcn_logf(w);
        nterm += c;
    }

    float sum = 0.5f * LN2_ * ((float)nterm - acc);   // BETA = 0.5

    // ---- obs part: 4 waves; wave=row; rows 0,1 buf A, rows 2,3 buf B ----
    if (tid < 256) {
        const int row  = tid >> 6;                    // 0..3, wave-uniform
        const int k    = (tid >> 3) & 7;
        const int seg  = tid & 7;
        const f16x2* tb   = (row < 2) ? t2a : t2b;
        const int    comp = row & 1;
        const int*   oc   = obs_cols + k * OBS_W_ + seg * 25;
        float pr = 1.0f;
        #pragma unroll 5
        for (int w = 0; w < 25; ++w) pr *= (float)tb[oc[w]][comp];
        #pragma unroll
        for (int off = 1; off < 8; off <<= 1) pr *= __shfl_xor(pr, off, 64);
        if (seg == 0) {
            float y  = observables[(size_t)(b0 + row) * K_ + k];
            float p  = clampp(pr);
            float w2 = fmaf(fmaf(y, -2.0f, 1.0f), p, 1.0f);
            sum += 0.5f * LN2_ * (1.0f - __builtin_amdgcn_logf(w2));   // 1-BETA
        }
    }

    // ---- block reduction ----
    for (int off = 32; off > 0; off >>= 1) sum += __shfl_down(sum, off, 64);
    const int lane = tid & 63, wv = tid >> 6;
    if (lane == 0) red[wv] = sum;
    __syncthreads();
    if (tid == 0) {
        float tot = 0.0f;
        #pragma unroll
        for (int i = 0; i < TPB / 64; ++i) tot += red[i];
        if (ATOMIC) atomicAdd(part, tot * (1.0f / (float)B_));
        else        part[blockIdx.x] = tot;
    }
}

__global__ __launch_bounds__(256) void decode_loss_reduce(
    const float* __restrict__ part, float* __restrict__ out, int n)
{
    __shared__ float red[4];
    const int tid = threadIdx.x;
    float s = 0.0f;
    for (int i = tid; i < n; i += 256) s += part[i];
    for (int off = 32; off > 0; off >>= 1) s += __shfl_down(s, off, 64);
    const int lane = tid & 63, wv = tid >> 6;
    if (lane == 0) red[wv] = s;
    __syncthreads();
    if (tid == 0) out[0] = (red[0] + red[1] + red[2] + red[3]) * (1.0f / (float)B_);
}

extern "C" void kernel_launch(void* const* d_in, const int* in_sizes, int n_in,
                              void* d_out, int out_size, void* d_ws, size_t ws_size,
                              hipStream_t stream) {
    const float* llrs        = (const float*)d_in[0];
    const float* syndromes   = (const float*)d_in[1];
    const float* observables = (const float*)d_in[2];
    const int*   chk_cols    = (const int*)d_in[3];
    const int*   obs_cols    = (const int*)d_in[4];
    float*       out         = (float*)d_out;

    const size_t lds_bytes = (size_t)N_ * 2 * sizeof(f16x2);   // 160 000 B
    const int    nblk      = B_ / 4;                           // 256

    (void)hipFuncSetAttribute((const void*)decode_loss_ws<false>,
        hipFuncAttributeMaxDynamicSharedMemorySize, (int)lds_bytes);
    (void)hipFuncSetAttribute((const void*)decode_loss_ws<true>,
        hipFuncAttributeMaxDynamicSharedMemorySize, (int)lds_bytes);

    if (ws_size >= (size_t)nblk * sizeof(float)) {
        float* part = (float*)d_ws;
        decode_loss_ws<false><<<nblk, TPB, lds_bytes, stream>>>(
            llrs, syndromes, observables, chk_cols, obs_cols, part);
        decode_loss_reduce<<<1, 256, 0, stream>>>(part, out, nblk);
    } else {
        hipMemsetAsync(out, 0, sizeof(float), stream);
        decode_loss_ws<true><<<nblk, TPB, lds_bytes, stream>>>(
            llrs, syndromes, observables, chk_cols, obs_cols, out);
    }
}

// Round 12
// 26.462 us; speedup vs baseline: 1.6563x; 1.1690x over previous
//
#include <hip/hip_runtime.h>

#define B_ 1024
#define N_ 20000
#define M_ 10000
#define K_ 8
#define OBS_W_ 200
#define TPB 1024

constexpr float EPS_   = 1e-6f;
constexpr float LN2_   = 0.69314718055994530942f;
constexpr float LOG2E_ = 1.4426950408889634f;

typedef _Float16 f16x4 __attribute__((ext_vector_type(4)));
typedef _Float16 f16x8 __attribute__((ext_vector_type(8)));

// tanh(x/2) = 1 - 2/(exp(x)+1), via hardware v_exp_f32 / v_rcp_f32.
__device__ __forceinline__ float tanh_half_fast(float x) {
    float e = __builtin_amdgcn_exp2f(x * LOG2E_);
    return 1.0f - 2.0f * __builtin_amdgcn_rcpf(e + 1.0f);
}

__device__ __forceinline__ float clampp(float p) {
    return fminf(fmaxf(p, -1.0f + EPS_), 1.0f - EPS_);
}

// ---- 4 rows per block, f16x4 in 160 KB LDS, grid 256 (R4 structure) -------
// Check loop merges 4 BCE terms into ONE v_log_f32:
//   sum_i [ln2 - ln(w_i)] = LN2 * (4 - log2(prod w_i)), w_i in [1e-6, 2).
template <bool ATOMIC>
__global__ __launch_bounds__(TPB) void decode_loss_m4(
    const float* __restrict__ llrs,
    const float* __restrict__ syndromes,
    const float* __restrict__ observables,
    const int*   __restrict__ chk_cols,
    const int*   __restrict__ obs_cols,
    float* __restrict__ part)
{
    extern __shared__ char smem_raw[];
    f16x4* t4 = reinterpret_cast<f16x4*>(smem_raw);
    __shared__ float red[TPB / 64];

    const int b0  = 4 * blockIdx.x;
    const int tid = threadIdx.x;

    // Stage tanh(llr/2) for 4 rows, interleaved: t4[n] = {r0,r1,r2,r3}(n).
    const float4* r0 = reinterpret_cast<const float4*>(llrs + (size_t)(b0 + 0) * N_);
    const float4* r1 = reinterpret_cast<const float4*>(llrs + (size_t)(b0 + 1) * N_);
    const float4* r2 = reinterpret_cast<const float4*>(llrs + (size_t)(b0 + 2) * N_);
    const float4* r3 = reinterpret_cast<const float4*>(llrs + (size_t)(b0 + 3) * N_);
    for (int i = tid; i < N_ / 4; i += TPB) {
        float4 a = r0[i], b = r1[i], c = r2[i], d = r3[i];
        f16x8 w01, w23;
        w01[0] = (_Float16)tanh_half_fast(a.x); w01[1] = (_Float16)tanh_half_fast(b.x);
        w01[2] = (_Float16)tanh_half_fast(c.x); w01[3] = (_Float16)tanh_half_fast(d.x);
        w01[4] = (_Float16)tanh_half_fast(a.y); w01[5] = (_Float16)tanh_half_fast(b.y);
        w01[6] = (_Float16)tanh_half_fast(c.y); w01[7] = (_Float16)tanh_half_fast(d.y);
        w23[0] = (_Float16)tanh_half_fast(a.z); w23[1] = (_Float16)tanh_half_fast(b.z);
        w23[2] = (_Float16)tanh_half_fast(c.z); w23[3] = (_Float16)tanh_half_fast(d.z);
        w23[4] = (_Float16)tanh_half_fast(a.w); w23[5] = (_Float16)tanh_half_fast(b.w);
        w23[6] = (_Float16)tanh_half_fast(c.w); w23[7] = (_Float16)tanh_half_fast(d.w);
        *reinterpret_cast<f16x8*>(&t4[4 * i + 0]) = w01;
        *reinterpret_cast<f16x8*>(&t4[4 * i + 2]) = w23;
    }
    __syncthreads();

    // Check part: one b64 gather yields all 4 rows' factors; one log per iter.
    float acc = 0.0f;    // sum of log2(w-products)
    int   cnt = 0;       // number of BCE terms accumulated
    const float* syn0 = syndromes + (size_t)(b0 + 0) * M_;
    const float* syn1 = syndromes + (size_t)(b0 + 1) * M_;
    const float* syn2 = syndromes + (size_t)(b0 + 2) * M_;
    const float* syn3 = syndromes + (size_t)(b0 + 3) * M_;
    const int4*  cc   = reinterpret_cast<const int4*>(chk_cols);
    for (int m = tid; m < M_; m += TPB) {
        int4 c0 = cc[2 * m];
        int4 c1 = cc[2 * m + 1];
        f16x4 g0 = t4[c0.x], g1 = t4[c0.y], g2 = t4[c0.z], g3 = t4[c0.w];
        f16x4 g4 = t4[c1.x], g5 = t4[c1.y], g6 = t4[c1.z], g7 = t4[c1.w];
        f16x4 p  = ((g0 * g1) * (g2 * g3)) * ((g4 * g5) * (g6 * g7));
        float w0 = fmaf(fmaf(syn0[m], -2.0f, 1.0f), clampp((float)p[0]), 1.0f);
        float w1 = fmaf(fmaf(syn1[m], -2.0f, 1.0f), clampp((float)p[1]), 1.0f);
        float w2 = fmaf(fmaf(syn2[m], -2.0f, 1.0f), clampp((float)p[2]), 1.0f);
        float w3 = fmaf(fmaf(syn3[m], -2.0f, 1.0f), clampp((float)p[3]), 1.0f);
        acc += __builtin_amdgcn_logf((w0 * w1) * (w2 * w3));  // log2, 1 trans
        cnt += 4;
    }
    float sum = 0.5f * LN2_ * ((float)cnt - acc);   // BETA = 0.5

    // Obs part: 4 waves; wave=row, 8 lanes per k, 25 elems per lane.
    if (tid < 256) {
        const int row = tid >> 6;          // 0..3, wave-uniform
        const int k   = (tid >> 3) & 7;
        const int seg = tid & 7;
        const int* oc = obs_cols + k * OBS_W_ + seg * 25;
        float pr = 1.0f;
        #pragma unroll 5
        for (int w = 0; w < 25; ++w) { f16x4 gg = t4[oc[w]]; pr *= (float)gg[row]; }
        #pragma unroll
        for (int off = 1; off < 8; off <<= 1) pr *= __shfl_xor(pr, off, 64);
        if (seg == 0) {
            float y  = observables[(size_t)(b0 + row) * K_ + k];
            float wv = fmaf(fmaf(y, -2.0f, 1.0f), clampp(pr), 1.0f);
            sum += 0.5f * LN2_ * (1.0f - __builtin_amdgcn_logf(wv));  // 1-BETA
        }
    }

    // Block reduction.
    for (int off = 32; off > 0; off >>= 1) sum += __shfl_down(sum, off, 64);
    const int lane = tid & 63, wv2 = tid >> 6;
    if (lane == 0) red[wv2] = sum;
    __syncthreads();
    if (tid == 0) {
        float tot = 0.0f;
        #pragma unroll
        for (int i = 0; i < TPB / 64; ++i) tot += red[i];
        if (ATOMIC) atomicAdd(part, tot * (1.0f / (float)B_));
        else        part[blockIdx.x] = tot;
    }
}

__global__ __launch_bounds__(256) void decode_loss_reduce(
    const float* __restrict__ part, float* __restrict__ out, int n)
{
    __shared__ float red[4];
    const int tid = threadIdx.x;
    float s = 0.0f;
    for (int i = tid; i < n; i += 256) s += part[i];
    for (int off = 32; off > 0; off >>= 1) s += __shfl_down(s, off, 64);
    const int lane = tid & 63, wv = tid >> 6;
    if (lane == 0) red[wv] = s;
    __syncthreads();
    if (tid == 0) out[0] = (red[0] + red[1] + red[2] + red[3]) * (1.0f / (float)B_);
}

extern "C" void kernel_launch(void* const* d_in, const int* in_sizes, int n_in,
                              void* d_out, int out_size, void* d_ws, size_t ws_size,
                              hipStream_t stream) {
    const float* llrs        = (const float*)d_in[0];
    const float* syndromes   = (const float*)d_in[1];
    const float* observables = (const float*)d_in[2];
    const int*   chk_cols    = (const int*)d_in[3];
    const int*   obs_cols    = (const int*)d_in[4];
    float*       out         = (float*)d_out;

    const size_t lds_bytes = (size_t)N_ * 8;   // 160 000 B (4 rows x f16)
    const int    nblk      = B_ / 4;           // 256

    (void)hipFuncSetAttribute((const void*)decode_loss_m4<false>,
        hipFuncAttributeMaxDynamicSharedMemorySize, (int)lds_bytes);
    (void)hipFuncSetAttribute((const void*)decode_loss_m4<true>,
        hipFuncAttributeMaxDynamicSharedMemorySize, (int)lds_bytes);

    if (ws_size >= (size_t)nblk * sizeof(float)) {
        float* part = (float*)d_ws;
        decode_loss_m4<false><<<nblk, TPB, lds_bytes, stream>>>(
            llrs, syndromes, observables, chk_cols, obs_cols, part);
        decode_loss_reduce<<<1, 256, 0, stream>>>(part, out, nblk);
    } else {
        hipMemsetAsync(out, 0, sizeof(float), stream);
        decode_loss_m4<true><<<nblk, TPB, lds_bytes, stream>>>(
            llrs, syndromes, observables, chk_cols, obs_cols, out);
    }
}